// Round 2
// 1963.279 us; speedup vs baseline: 1.3257x; 1.3257x over previous
//
#include <hip/hip_runtime.h>

#define S 3136
#define E 1024
#define H 16
#define D 64
// S/32 = 98, S/64 = 49, E/64 = 16 -- all exact, no bounds checks needed.

typedef __attribute__((ext_vector_type(8))) short bf8_t;  // 8 bf16 (4 VGPRs)
typedef __attribute__((ext_vector_type(4))) float f32x4;  // 4 fp32

static __device__ __forceinline__ unsigned short f2bf(float f) {
    unsigned int u = __float_as_uint(f);
    u += 0x7fff + ((u >> 16) & 1);   // round-to-nearest-even
    return (unsigned short)(u >> 16);
}
static __device__ __forceinline__ float bf2f(unsigned short h) {
    return __uint_as_float(((unsigned int)h) << 16);
}

// C[M x N] = A[M x K] * B[N x K]^T   (row-major A, B; i.e. C = A @ B.T)
template<int N, int K>
__global__ __launch_bounds__(256) void gemm_nt(const float* __restrict__ A,
                                               const float* __restrict__ B,
                                               float* __restrict__ C) {
    __shared__ float As[16 * 68];   // As[k][m], padded stride 68
    __shared__ float Bs[16 * 68];   // Bs[k][n]
    const int tid = threadIdx.x;
    const int tx = tid & 15, ty = tid >> 4;
    const int m0 = blockIdx.y * 64, n0 = blockIdx.x * 64;
    float c[4][4] = {};
    for (int kt = 0; kt < K; kt += 16) {
#pragma unroll
        for (int i = 0; i < 4; ++i) {
            int e = tid + i * 256;
            int r = e >> 4, kk = e & 15;
            As[kk * 68 + r] = A[(m0 + r) * K + kt + kk];
            Bs[kk * 68 + r] = B[(n0 + r) * K + kt + kk];
        }
        __syncthreads();
#pragma unroll
        for (int kk = 0; kk < 16; ++kk) {
            const float4 a = *(const float4*)&As[kk * 68 + ty * 4];
            const float4 b = *(const float4*)&Bs[kk * 68 + tx * 4];
            float av[4] = {a.x, a.y, a.z, a.w};
            float bv[4] = {b.x, b.y, b.z, b.w};
#pragma unroll
            for (int i = 0; i < 4; ++i)
#pragma unroll
                for (int j = 0; j < 4; ++j)
                    c[i][j] += av[i] * bv[j];
        }
        __syncthreads();
    }
#pragma unroll
    for (int i = 0; i < 4; ++i) {
        float4 v = make_float4(c[i][0], c[i][1], c[i][2], c[i][3]);
        *(float4*)&C[(m0 + ty * 4 + i) * N + n0 + tx * 4] = v;
    }
}

// In-place RoPE on Q and K. rotate_half: rot[i] = -x[i+32] (i<32), x[i-32] (i>=32)
__global__ __launch_bounds__(256) void rope_kernel(float* __restrict__ Q, float* __restrict__ Kp,
                                                   const float* __restrict__ cosp,
                                                   const float* __restrict__ sinp) {
    int t = blockIdx.x * 256 + threadIdx.x;   // S*H*32 threads
    int i = t & 31;
    int h = (t >> 5) & 15;
    int s = t >> 9;
    int base = s * E + h * D;
    float c0 = cosp[s * D + i], c1 = cosp[s * D + i + 32];
    float s0 = sinp[s * D + i], s1 = sinp[s * D + i + 32];
    float q0 = Q[base + i], q1 = Q[base + i + 32];
    Q[base + i]      = q0 * c0 - q1 * s0;
    Q[base + i + 32] = q1 * c1 + q0 * s1;
    float k0 = Kp[base + i], k1 = Kp[base + i + 32];
    Kp[base + i]      = k0 * c0 - k1 * s0;
    Kp[base + i + 32] = k1 * c1 + k0 * s1;
}

// Pass A (MFMA): per (head, 64 q rows): raw scaled scores -> W, online (m,l) per row.
// fp32 emulated via split-bf16: x = hi + lo; x*y ~= hi*hi + hi*lo + lo*hi (3 bf16 MFMAs).
// mfma_f32_16x16x32_bf16: A row = lane&15, k = (lane>>4)*8+i (K-slot order cancels
// between A and B); D: col = lane&15, row = (lane>>4)*4 + reg (HW-verified mapping).
__global__ __launch_bounds__(256) void scores_mfma(const float* __restrict__ Q,
                                                   const float* __restrict__ Kp,
                                                   float* __restrict__ W,
                                                   float* __restrict__ Mv,
                                                   float* __restrict__ Lv) {
    // K tile staged as bf16 hi/lo, [64 rows][64 d]; 16B units XOR-swizzled within each
    // row (unit ^= row&7) so fragment ds_read_b128 (16 lanes, same unit col, rows 0..15)
    // spreads over 8 bank groups instead of a 16-way conflict.
    __shared__ __align__(16) unsigned short Khs[64 * 64];
    __shared__ __align__(16) unsigned short Kls[64 * 64];
    const int tid  = threadIdx.x;
    const int lane = tid & 63;
    const int wid  = tid >> 6;          // 4 waves, wave w owns q rows w*16..w*16+15
    const int q0   = blockIdx.x * 64;
    const int h    = blockIdx.y;

    // ---- Q fragments (hi/lo, 2 K-chunks of 32) held in registers all kernel ----
    const int qrow_frag = q0 + wid * 16 + (lane & 15);
    const float* qp = Q + (size_t)qrow_frag * E + h * D + ((lane >> 4) * 8);
    bf8_t qhi[2], qlo[2];
#pragma unroll
    for (int c = 0; c < 2; ++c) {
        float4 a = *(const float4*)(qp + c * 32);
        float4 b = *(const float4*)(qp + c * 32 + 4);
        float f[8] = {a.x, a.y, a.z, a.w, b.x, b.y, b.z, b.w};
#pragma unroll
        for (int i = 0; i < 8; ++i) {
            unsigned short hi = f2bf(f[i]);
            qhi[c][i] = (short)hi;
            qlo[c][i] = (short)f2bf(f[i] - bf2f(hi));
        }
    }

    // staging coords: thread loads 16 consecutive fp32 of one K row (coalesced)
    const int sr  = tid >> 2;           // row 0..63
    const int sd  = (tid & 3) * 16;     // d offset 0,16,32,48
    const int su0 = (tid & 3) * 2;      // first 16B unit (0,2,4,6)

    float mreg[4] = {-1e30f, -1e30f, -1e30f, -1e30f};
    float lreg[4] = {0.f, 0.f, 0.f, 0.f};
    const int wq0 = q0 + wid * 16 + ((lane >> 4) << 2);  // first of 4 rows this lane owns
    float* wout = W + (size_t)h * S * S;

    for (int kt = 0; kt < S; kt += 64) {
        // ---- stage K tile: global fp32 -> registers -> bf16 hi/lo -> swizzled LDS ----
        const float* kp = Kp + (size_t)(kt + sr) * E + h * D + sd;
        float4 a0 = *(const float4*)(kp);
        float4 a1 = *(const float4*)(kp + 4);
        float4 a2 = *(const float4*)(kp + 8);
        float4 a3 = *(const float4*)(kp + 12);
        float f[16] = {a0.x,a0.y,a0.z,a0.w, a1.x,a1.y,a1.z,a1.w,
                       a2.x,a2.y,a2.z,a2.w, a3.x,a3.y,a3.z,a3.w};
        unsigned int hw[8], lw[8];
#pragma unroll
        for (int j2 = 0; j2 < 8; ++j2) {
            unsigned short h0 = f2bf(f[2 * j2]);
            unsigned short h1 = f2bf(f[2 * j2 + 1]);
            unsigned short l0 = f2bf(f[2 * j2]     - bf2f(h0));
            unsigned short l1 = f2bf(f[2 * j2 + 1] - bf2f(h1));
            hw[j2] = (unsigned int)h0 | ((unsigned int)h1 << 16);
            lw[j2] = (unsigned int)l0 | ((unsigned int)l1 << 16);
        }
        const int p0 = ((su0     ^ (sr & 7)) << 3);
        const int p1 = (((su0+1) ^ (sr & 7)) << 3);
        *(uint4*)&Khs[sr * 64 + p0] = make_uint4(hw[0], hw[1], hw[2], hw[3]);
        *(uint4*)&Khs[sr * 64 + p1] = make_uint4(hw[4], hw[5], hw[6], hw[7]);
        *(uint4*)&Kls[sr * 64 + p0] = make_uint4(lw[0], lw[1], lw[2], lw[3]);
        *(uint4*)&Kls[sr * 64 + p1] = make_uint4(lw[4], lw[5], lw[6], lw[7]);
        __syncthreads();

        // ---- MFMA: 4 n-subtiles x 2 K-chunks x 3 split products ----
        f32x4 acc[4];
#pragma unroll
        for (int t = 0; t < 4; ++t) acc[t] = (f32x4)(0.f);
#pragma unroll
        for (int c = 0; c < 2; ++c) {
#pragma unroll
            for (int t = 0; t < 4; ++t) {
                const int n   = t * 16 + (lane & 15);
                const int u   = c * 4 + (lane >> 4);
                const int idx = n * 64 + ((u ^ (n & 7)) << 3);
                bf8_t kh = *(const bf8_t*)&Khs[idx];
                bf8_t kl = *(const bf8_t*)&Kls[idx];
                acc[t] = __builtin_amdgcn_mfma_f32_16x16x32_bf16(qhi[c], kh, acc[t], 0, 0, 0);
                acc[t] = __builtin_amdgcn_mfma_f32_16x16x32_bf16(qlo[c], kh, acc[t], 0, 0, 0);
                acc[t] = __builtin_amdgcn_mfma_f32_16x16x32_bf16(qhi[c], kl, acc[t], 0, 0, 0);
            }
        }

        // ---- scale, store raw scores, fold into online (m,l) ----
        const int col = kt + (lane & 15);
#pragma unroll
        for (int j = 0; j < 4; ++j) {
            float s0 = acc[0][j] * 0.125f;
            float s1 = acc[1][j] * 0.125f;
            float s2 = acc[2][j] * 0.125f;
            float s3 = acc[3][j] * 0.125f;
            float* wr = wout + (size_t)(wq0 + j) * S + col;
            wr[0] = s0; wr[16] = s1; wr[32] = s2; wr[48] = s3;
            float tm = fmaxf(fmaxf(s0, s1), fmaxf(s2, s3));
            float nm = fmaxf(mreg[j], tm);
            lreg[j] = lreg[j] * __expf(mreg[j] - nm)
                    + __expf(s0 - nm) + __expf(s1 - nm)
                    + __expf(s2 - nm) + __expf(s3 - nm);
            mreg[j] = nm;
        }
        __syncthreads();
    }

    // ---- merge (m,l) across the 16 lanes of each row group ----
#pragma unroll
    for (int off = 1; off < 16; off <<= 1) {
#pragma unroll
        for (int j = 0; j < 4; ++j) {
            float om = __shfl_xor(mreg[j], off, 64);
            float ol = __shfl_xor(lreg[j], off, 64);
            float nm = fmaxf(mreg[j], om);
            lreg[j] = lreg[j] * __expf(mreg[j] - nm) + ol * __expf(om - nm);
            mreg[j] = nm;
        }
    }
    if ((lane & 15) == 0) {
#pragma unroll
        for (int j = 0; j < 4; ++j) {
            Mv[h * S + wq0 + j] = mreg[j];
            Lv[h * S + wq0 + j] = lreg[j];
        }
    }
}

// Pass B: normalize W in place (w = exp(s-m)/l) and O = W @ V per head.
__global__ __launch_bounds__(256) void av_pass(const float* __restrict__ V,
                                               float* __restrict__ W,
                                               const float* __restrict__ Mv,
                                               const float* __restrict__ Lv,
                                               float* __restrict__ O) {
    __shared__ float Vs[32 * 64];
    __shared__ float Ss[32 * 33];
    __shared__ float sm[32], srl[32];
    const int tid = threadIdx.x;
    const int q0 = blockIdx.x * 32;
    const int h  = blockIdx.y;
    if (tid < 32) {
        sm[tid]  = Mv[h * S + q0 + tid];
        srl[tid] = 1.0f / Lv[h * S + q0 + tid];
    }
    __syncthreads();
    const int qi = tid >> 3;  // 0..31 (q row)
    const int tx = tid & 7;   // 0..7  (8 d-columns each)
    float acc[8] = {};
    const int wbase = h * S * S;
    for (int kt = 0; kt < S; kt += 32) {
#pragma unroll
        for (int i = 0; i < 8; ++i) {
            int e = tid + i * 256;
            int r = e >> 6, c = e & 63;
            Vs[r * 64 + c] = V[(kt + r) * E + h * D + c];
        }
#pragma unroll
        for (int i = 0; i < 4; ++i) {
            int e = tid + i * 256;
            int r = e >> 5, c = e & 31;
            int gi = wbase + (q0 + r) * S + kt + c;
            float s = W[gi];
            float w = __expf(s - sm[r]) * srl[r];
            W[gi] = w;
            Ss[r * 33 + c] = w;
        }
        __syncthreads();
#pragma unroll
        for (int kk = 0; kk < 32; ++kk) {
            float w = Ss[qi * 33 + kk];
            const float4* vp = (const float4*)&Vs[kk * 64 + tx * 8];
            float4 v0 = vp[0], v1 = vp[1];
            acc[0] += w * v0.x; acc[1] += w * v0.y; acc[2] += w * v0.z; acc[3] += w * v0.w;
            acc[4] += w * v1.x; acc[5] += w * v1.y; acc[6] += w * v1.z; acc[7] += w * v1.w;
        }
        __syncthreads();
    }
    float* op = &O[(q0 + qi) * E + h * D + tx * 8];
    *(float4*)op       = make_float4(acc[0], acc[1], acc[2], acc[3]);
    *((float4*)op + 1) = make_float4(acc[4], acc[5], acc[6], acc[7]);
}

extern "C" void kernel_launch(void* const* d_in, const int* in_sizes, int n_in,
                              void* d_out, int out_size, void* d_ws, size_t ws_size,
                              hipStream_t stream) {
    const float* hs   = (const float*)d_in[0];
    const float* cosp = (const float*)d_in[1];
    const float* sinp = (const float*)d_in[2];
    const float* wq   = (const float*)d_in[3];
    const float* wk   = (const float*)d_in[4];
    const float* wv   = (const float*)d_in[5];
    const float* wo   = (const float*)d_in[6];

    float* out = (float*)d_out;                 // attn_output: S*E floats
    float* W   = out + (size_t)S * E;           // attn_weights: H*S*S floats

    float* ws = (float*)d_ws;
    float* Q  = ws;                             // S*E
    float* Kp = ws + (size_t)S * E;             // S*E
    float* V  = ws + 2 * (size_t)S * E;         // S*E
    float* O  = Q;                              // reuse Q region (Q dead after scores)
    float* Mv = ws + 3 * (size_t)S * E;         // H*S
    float* Lv = Mv + H * S;                     // H*S

    dim3 gproj(E / 64, S / 64);
    gemm_nt<E, E><<<gproj, 256, 0, stream>>>(hs, wq, Q);
    gemm_nt<E, E><<<gproj, 256, 0, stream>>>(hs, wk, Kp);
    gemm_nt<E, E><<<gproj, 256, 0, stream>>>(hs, wv, V);

    rope_kernel<<<(S * H * 32) / 256, 256, 0, stream>>>(Q, Kp, cosp, sinp);

    dim3 gsc(S / 64, H);
    scores_mfma<<<gsc, 256, 0, stream>>>(Q, Kp, W, Mv, Lv);

    dim3 gattn(S / 32, H);
    av_pass<<<gattn, 256, 0, stream>>>(V, W, Mv, Lv, O);

    gemm_nt<E, E><<<gproj, 256, 0, stream>>>(O, wo, out);
}

// Round 3
// 1565.461 us; speedup vs baseline: 1.6626x; 1.2541x over previous
//
#include <hip/hip_runtime.h>

#define S 3136
#define E 1024
#define H 16
#define D 64
// S/32 = 98, S/64 = 49, E/64 = 16 -- all exact, no bounds checks needed.

typedef __attribute__((ext_vector_type(8))) short bf8_t;  // 8 bf16 (4 VGPRs)
typedef __attribute__((ext_vector_type(4))) float f32x4;  // 4 fp32

static __device__ __forceinline__ unsigned short f2bf(float f) {
    unsigned int u = __float_as_uint(f);
    u += 0x7fff + ((u >> 16) & 1);   // round-to-nearest-even
    return (unsigned short)(u >> 16);
}
static __device__ __forceinline__ float bf2f(unsigned short h) {
    return __uint_as_float(((unsigned int)h) << 16);
}
static __device__ __forceinline__ unsigned int pack2(unsigned short a, unsigned short b) {
    return (unsigned int)a | ((unsigned int)b << 16);
}

// C[M x N] = A[M x K] * B[N x K]^T   (row-major A, B; i.e. C = A @ B.T)
template<int N, int K>
__global__ __launch_bounds__(256) void gemm_nt(const float* __restrict__ A,
                                               const float* __restrict__ B,
                                               float* __restrict__ C) {
    __shared__ float As[16 * 68];   // As[k][m], padded stride 68
    __shared__ float Bs[16 * 68];   // Bs[k][n]
    const int tid = threadIdx.x;
    const int tx = tid & 15, ty = tid >> 4;
    const int m0 = blockIdx.y * 64, n0 = blockIdx.x * 64;
    float c[4][4] = {};
    for (int kt = 0; kt < K; kt += 16) {
#pragma unroll
        for (int i = 0; i < 4; ++i) {
            int e = tid + i * 256;
            int r = e >> 4, kk = e & 15;
            As[kk * 68 + r] = A[(m0 + r) * K + kt + kk];
            Bs[kk * 68 + r] = B[(n0 + r) * K + kt + kk];
        }
        __syncthreads();
#pragma unroll
        for (int kk = 0; kk < 16; ++kk) {
            const float4 a = *(const float4*)&As[kk * 68 + ty * 4];
            const float4 b = *(const float4*)&Bs[kk * 68 + tx * 4];
            float av[4] = {a.x, a.y, a.z, a.w};
            float bv[4] = {b.x, b.y, b.z, b.w};
#pragma unroll
            for (int i = 0; i < 4; ++i)
#pragma unroll
                for (int j = 0; j < 4; ++j)
                    c[i][j] += av[i] * bv[j];
        }
        __syncthreads();
    }
#pragma unroll
    for (int i = 0; i < 4; ++i) {
        float4 v = make_float4(c[i][0], c[i][1], c[i][2], c[i][3]);
        *(float4*)&C[(m0 + ty * 4 + i) * N + n0 + tx * 4] = v;
    }
}

// In-place RoPE on Q and K. rotate_half: rot[i] = -x[i+32] (i<32), x[i-32] (i>=32)
__global__ __launch_bounds__(256) void rope_kernel(float* __restrict__ Q, float* __restrict__ Kp,
                                                   const float* __restrict__ cosp,
                                                   const float* __restrict__ sinp) {
    int t = blockIdx.x * 256 + threadIdx.x;   // S*H*32 threads
    int i = t & 31;
    int h = (t >> 5) & 15;
    int s = t >> 9;
    int base = s * E + h * D;
    float c0 = cosp[s * D + i], c1 = cosp[s * D + i + 32];
    float s0 = sinp[s * D + i], s1 = sinp[s * D + i + 32];
    float q0 = Q[base + i], q1 = Q[base + i + 32];
    Q[base + i]      = q0 * c0 - q1 * s0;
    Q[base + i + 32] = q1 * c1 + q0 * s1;
    float k0 = Kp[base + i], k1 = Kp[base + i + 32];
    Kp[base + i]      = k0 * c0 - k1 * s0;
    Kp[base + i + 32] = k1 * c1 + k0 * s1;
}

// Pass A (MFMA): per (head, 64 q rows): raw scaled scores -> W, online (m,l) per row.
// fp32 emulated via split-bf16: x = hi + lo; x*y ~= hi*hi + hi*lo + lo*hi (3 bf16 MFMAs).
__global__ __launch_bounds__(256) void scores_mfma(const float* __restrict__ Q,
                                                   const float* __restrict__ Kp,
                                                   float* __restrict__ W,
                                                   float* __restrict__ Mv,
                                                   float* __restrict__ Lv) {
    __shared__ __align__(16) unsigned short Khs[64 * 64];
    __shared__ __align__(16) unsigned short Kls[64 * 64];
    const int tid  = threadIdx.x;
    const int lane = tid & 63;
    const int wid  = tid >> 6;          // 4 waves, wave w owns q rows w*16..w*16+15
    const int q0   = blockIdx.x * 64;
    const int h    = blockIdx.y;

    // ---- Q fragments (hi/lo, 2 K-chunks of 32) held in registers all kernel ----
    const int qrow_frag = q0 + wid * 16 + (lane & 15);
    const float* qp = Q + (size_t)qrow_frag * E + h * D + ((lane >> 4) * 8);
    bf8_t qhi[2], qlo[2];
#pragma unroll
    for (int c = 0; c < 2; ++c) {
        float4 a = *(const float4*)(qp + c * 32);
        float4 b = *(const float4*)(qp + c * 32 + 4);
        float f[8] = {a.x, a.y, a.z, a.w, b.x, b.y, b.z, b.w};
#pragma unroll
        for (int i = 0; i < 8; ++i) {
            unsigned short hi = f2bf(f[i]);
            qhi[c][i] = (short)hi;
            qlo[c][i] = (short)f2bf(f[i] - bf2f(hi));
        }
    }

    const int sr  = tid >> 2;           // staging row 0..63
    const int sd  = (tid & 3) * 16;     // d offset
    const int su0 = (tid & 3) * 2;      // first 16B unit

    float mreg[4] = {-1e30f, -1e30f, -1e30f, -1e30f};
    float lreg[4] = {0.f, 0.f, 0.f, 0.f};
    const int wq0 = q0 + wid * 16 + ((lane >> 4) << 2);
    float* wout = W + (size_t)h * S * S;

    for (int kt = 0; kt < S; kt += 64) {
        const float* kp = Kp + (size_t)(kt + sr) * E + h * D + sd;
        float4 a0 = *(const float4*)(kp);
        float4 a1 = *(const float4*)(kp + 4);
        float4 a2 = *(const float4*)(kp + 8);
        float4 a3 = *(const float4*)(kp + 12);
        float f[16] = {a0.x,a0.y,a0.z,a0.w, a1.x,a1.y,a1.z,a1.w,
                       a2.x,a2.y,a2.z,a2.w, a3.x,a3.y,a3.z,a3.w};
        unsigned int hw[8], lw[8];
#pragma unroll
        for (int j2 = 0; j2 < 8; ++j2) {
            unsigned short h0 = f2bf(f[2 * j2]);
            unsigned short h1 = f2bf(f[2 * j2 + 1]);
            unsigned short l0 = f2bf(f[2 * j2]     - bf2f(h0));
            unsigned short l1 = f2bf(f[2 * j2 + 1] - bf2f(h1));
            hw[j2] = pack2(h0, h1);
            lw[j2] = pack2(l0, l1);
        }
        const int p0 = ((su0     ^ (sr & 7)) << 3);
        const int p1 = (((su0+1) ^ (sr & 7)) << 3);
        *(uint4*)&Khs[sr * 64 + p0] = make_uint4(hw[0], hw[1], hw[2], hw[3]);
        *(uint4*)&Khs[sr * 64 + p1] = make_uint4(hw[4], hw[5], hw[6], hw[7]);
        *(uint4*)&Kls[sr * 64 + p0] = make_uint4(lw[0], lw[1], lw[2], lw[3]);
        *(uint4*)&Kls[sr * 64 + p1] = make_uint4(lw[4], lw[5], lw[6], lw[7]);
        __syncthreads();

        f32x4 acc[4];
#pragma unroll
        for (int t = 0; t < 4; ++t) acc[t] = (f32x4)(0.f);
#pragma unroll
        for (int c = 0; c < 2; ++c) {
#pragma unroll
            for (int t = 0; t < 4; ++t) {
                const int n   = t * 16 + (lane & 15);
                const int u   = c * 4 + (lane >> 4);
                const int idx = n * 64 + ((u ^ (n & 7)) << 3);
                bf8_t kh = *(const bf8_t*)&Khs[idx];
                bf8_t kl = *(const bf8_t*)&Kls[idx];
                acc[t] = __builtin_amdgcn_mfma_f32_16x16x32_bf16(qhi[c], kh, acc[t], 0, 0, 0);
                acc[t] = __builtin_amdgcn_mfma_f32_16x16x32_bf16(qlo[c], kh, acc[t], 0, 0, 0);
                acc[t] = __builtin_amdgcn_mfma_f32_16x16x32_bf16(qhi[c], kl, acc[t], 0, 0, 0);
            }
        }

        const int col = kt + (lane & 15);
#pragma unroll
        for (int j = 0; j < 4; ++j) {
            float s0 = acc[0][j] * 0.125f;
            float s1 = acc[1][j] * 0.125f;
            float s2 = acc[2][j] * 0.125f;
            float s3 = acc[3][j] * 0.125f;
            float* wr = wout + (size_t)(wq0 + j) * S + col;
            wr[0] = s0; wr[16] = s1; wr[32] = s2; wr[48] = s3;
            float tm = fmaxf(fmaxf(s0, s1), fmaxf(s2, s3));
            float nm = fmaxf(mreg[j], tm);
            lreg[j] = lreg[j] * __expf(mreg[j] - nm)
                    + __expf(s0 - nm) + __expf(s1 - nm)
                    + __expf(s2 - nm) + __expf(s3 - nm);
            mreg[j] = nm;
        }
        __syncthreads();
    }

#pragma unroll
    for (int off = 1; off < 16; off <<= 1) {
#pragma unroll
        for (int j = 0; j < 4; ++j) {
            float om = __shfl_xor(mreg[j], off, 64);
            float ol = __shfl_xor(lreg[j], off, 64);
            float nm = fmaxf(mreg[j], om);
            lreg[j] = lreg[j] * __expf(mreg[j] - nm) + ol * __expf(om - nm);
            mreg[j] = nm;
        }
    }
    if ((lane & 15) == 0) {
#pragma unroll
        for (int j = 0; j < 4; ++j) {
            Mv[h * S + wq0 + j] = mreg[j];
            Lv[h * S + wq0 + j] = lreg[j];
        }
    }
}

// Pass B (MFMA): normalize W in place (w = exp(s-m)/l) and O = W @ V per head.
// Same split-bf16 emulation; P and V^T staged in XOR-swizzled LDS.
__global__ __launch_bounds__(256) void av_mfma(const float* __restrict__ V,
                                               float* __restrict__ W,
                                               const float* __restrict__ Mv,
                                               const float* __restrict__ Lv,
                                               float* __restrict__ O) {
    __shared__ __align__(16) unsigned short Phs[64 * 64];   // P[q][kv] bf16-hi, swizzled
    __shared__ __align__(16) unsigned short Pls[64 * 64];   // P lo
    __shared__ __align__(16) unsigned short Vths[64 * 64];  // V^T[d][kv] bf16-hi, swizzled
    __shared__ __align__(16) unsigned short Vtls[64 * 64];  // V^T lo
    __shared__ float sm[64], srl[64];
    const int tid  = threadIdx.x;
    const int lane = tid & 63;
    const int wid  = tid >> 6;
    const int q0   = blockIdx.x * 64;
    const int h    = blockIdx.y;

    if (tid < 64) {
        sm[tid]  = Mv[h * S + q0 + tid];
        srl[tid] = 1.0f / Lv[h * S + q0 + tid];
    }
    __syncthreads();

    // exp-phase coords: thread owns (q row = tid>>2, 16 consecutive kv)
    const int eq   = tid >> 2;
    const int ec0  = (tid & 3) * 16;
    const int epu0 = (tid & 3) * 2;
    // V-staging coords: thread owns (4 consecutive kv rows, 4 consecutive d)
    const int vd0 = (tid & 15) * 4;
    const int vk0 = (tid >> 4) * 4;

    float* wout = W + (size_t)h * S * S;
    const int kg = lane >> 4;               // k-group within fragment
    const int arow = wid * 16 + (lane & 15);// A-fragment q row (local)

    f32x4 acc[4];
#pragma unroll
    for (int t = 0; t < 4; ++t) acc[t] = (f32x4)(0.f);

    for (int kt = 0; kt < S; kt += 64) {
        // ---- read raw scores, softmax-finalize, write W, pack P into LDS ----
        {
            float* wrow = wout + (size_t)(q0 + eq) * S + kt + ec0;
            float4 r0 = *(const float4*)(wrow);
            float4 r1 = *(const float4*)(wrow + 4);
            float4 r2 = *(const float4*)(wrow + 8);
            float4 r3 = *(const float4*)(wrow + 12);
            float f[16] = {r0.x,r0.y,r0.z,r0.w, r1.x,r1.y,r1.z,r1.w,
                           r2.x,r2.y,r2.z,r2.w, r3.x,r3.y,r3.z,r3.w};
            const float mm = sm[eq], rl = srl[eq];
            float w[16];
#pragma unroll
            for (int j = 0; j < 16; ++j) w[j] = __expf(f[j] - mm) * rl;
            *(float4*)(wrow)      = make_float4(w[0],  w[1],  w[2],  w[3]);
            *(float4*)(wrow + 4)  = make_float4(w[4],  w[5],  w[6],  w[7]);
            *(float4*)(wrow + 8)  = make_float4(w[8],  w[9],  w[10], w[11]);
            *(float4*)(wrow + 12) = make_float4(w[12], w[13], w[14], w[15]);
            unsigned int hw[8], lw[8];
#pragma unroll
            for (int j2 = 0; j2 < 8; ++j2) {
                unsigned short h0 = f2bf(w[2 * j2]);
                unsigned short h1 = f2bf(w[2 * j2 + 1]);
                unsigned short l0 = f2bf(w[2 * j2]     - bf2f(h0));
                unsigned short l1 = f2bf(w[2 * j2 + 1] - bf2f(h1));
                hw[j2] = pack2(h0, h1);
                lw[j2] = pack2(l0, l1);
            }
            const int pb0 = eq * 64 + ((epu0       ^ (eq & 7)) << 3);
            const int pb1 = eq * 64 + (((epu0 + 1) ^ (eq & 7)) << 3);
            *(uint4*)&Phs[pb0] = make_uint4(hw[0], hw[1], hw[2], hw[3]);
            *(uint4*)&Phs[pb1] = make_uint4(hw[4], hw[5], hw[6], hw[7]);
            *(uint4*)&Pls[pb0] = make_uint4(lw[0], lw[1], lw[2], lw[3]);
            *(uint4*)&Pls[pb1] = make_uint4(lw[4], lw[5], lw[6], lw[7]);
        }
        // ---- stage V^T tile (bf16 hi/lo, swizzled) ----
        {
            const float* vp = V + (size_t)(kt + vk0) * E + h * D + vd0;
            float vr[4][4];
#pragma unroll
            for (int r = 0; r < 4; ++r) {
                float4 t = *(const float4*)(vp + (size_t)r * E);
                vr[r][0] = t.x; vr[r][1] = t.y; vr[r][2] = t.z; vr[r][3] = t.w;
            }
#pragma unroll
            for (int d_ = 0; d_ < 4; ++d_) {
                const int d = vd0 + d_;
                unsigned short h0 = f2bf(vr[0][d_]);
                unsigned short h1 = f2bf(vr[1][d_]);
                unsigned short h2 = f2bf(vr[2][d_]);
                unsigned short h3 = f2bf(vr[3][d_]);
                unsigned short l0 = f2bf(vr[0][d_] - bf2f(h0));
                unsigned short l1 = f2bf(vr[1][d_] - bf2f(h1));
                unsigned short l2 = f2bf(vr[2][d_] - bf2f(h2));
                unsigned short l3 = f2bf(vr[3][d_] - bf2f(h3));
                const int va = d * 64 + (((vk0 >> 3) ^ (d & 7)) << 3) + (vk0 & 7);
                *(uint2*)&Vths[va] = make_uint2(pack2(h0, h1), pack2(h2, h3));
                *(uint2*)&Vtls[va] = make_uint2(pack2(l0, l1), pack2(l2, l3));
            }
        }
        __syncthreads();

        // ---- MFMA: O[64q x 64d] += P @ V ----
#pragma unroll
        for (int kc = 0; kc < 2; ++kc) {
            const int au = ((kc * 4 + kg) ^ (arow & 7)) << 3;
            bf8_t ph = *(const bf8_t*)&Phs[arow * 64 + au];
            bf8_t pl = *(const bf8_t*)&Pls[arow * 64 + au];
#pragma unroll
            for (int t = 0; t < 4; ++t) {
                const int d  = t * 16 + (lane & 15);
                const int bu = ((kc * 4 + kg) ^ (d & 7)) << 3;
                bf8_t vh = *(const bf8_t*)&Vths[d * 64 + bu];
                bf8_t vl = *(const bf8_t*)&Vtls[d * 64 + bu];
                acc[t] = __builtin_amdgcn_mfma_f32_16x16x32_bf16(ph, vh, acc[t], 0, 0, 0);
                acc[t] = __builtin_amdgcn_mfma_f32_16x16x32_bf16(ph, vl, acc[t], 0, 0, 0);
                acc[t] = __builtin_amdgcn_mfma_f32_16x16x32_bf16(pl, vh, acc[t], 0, 0, 0);
            }
        }
        __syncthreads();
    }

    // ---- write O: D mapping col=lane&15 (d within subtile), row=(lane>>4)*4+reg (q) ----
    const int oq0 = q0 + wid * 16 + (kg << 2);
#pragma unroll
    for (int j = 0; j < 4; ++j) {
        float* op = O + (size_t)(oq0 + j) * E + h * D + (lane & 15);
#pragma unroll
        for (int t = 0; t < 4; ++t)
            op[t * 16] = acc[t][j];
    }
}

extern "C" void kernel_launch(void* const* d_in, const int* in_sizes, int n_in,
                              void* d_out, int out_size, void* d_ws, size_t ws_size,
                              hipStream_t stream) {
    const float* hs   = (const float*)d_in[0];
    const float* cosp = (const float*)d_in[1];
    const float* sinp = (const float*)d_in[2];
    const float* wq   = (const float*)d_in[3];
    const float* wk   = (const float*)d_in[4];
    const float* wv   = (const float*)d_in[5];
    const float* wo   = (const float*)d_in[6];

    float* out = (float*)d_out;                 // attn_output: S*E floats
    float* W   = out + (size_t)S * E;           // attn_weights: H*S*S floats

    float* ws = (float*)d_ws;
    float* Q  = ws;                             // S*E
    float* Kp = ws + (size_t)S * E;             // S*E
    float* V  = ws + 2 * (size_t)S * E;         // S*E
    float* O  = Q;                              // reuse Q region (Q dead after scores)
    float* Mv = ws + 3 * (size_t)S * E;         // H*S
    float* Lv = Mv + H * S;                     // H*S

    dim3 gproj(E / 64, S / 64);
    gemm_nt<E, E><<<gproj, 256, 0, stream>>>(hs, wq, Q);
    gemm_nt<E, E><<<gproj, 256, 0, stream>>>(hs, wk, Kp);
    gemm_nt<E, E><<<gproj, 256, 0, stream>>>(hs, wv, V);

    rope_kernel<<<(S * H * 32) / 256, 256, 0, stream>>>(Q, Kp, cosp, sinp);

    dim3 gsc(S / 64, H);
    scores_mfma<<<gsc, 256, 0, stream>>>(Q, Kp, W, Mv, Lv);

    dim3 gav(S / 64, H);
    av_mfma<<<gav, 256, 0, stream>>>(V, W, Mv, Lv, O);

    gemm_nt<E, E><<<gproj, 256, 0, stream>>>(O, wo, out);
}

// Round 4
// 1273.606 us; speedup vs baseline: 2.0436x; 1.2292x over previous
//
#include <hip/hip_runtime.h>

#define S 3136
#define E 1024
#define H 16
#define D 64
// S/32 = 98, S/64 = 49, E/64 = 16 -- all exact, no bounds checks needed.

typedef __attribute__((ext_vector_type(8))) short bf8_t;  // 8 bf16 (4 VGPRs)
typedef __attribute__((ext_vector_type(4))) float f32x4;  // 4 fp32

static __device__ __forceinline__ unsigned short f2bf(float f) {
    unsigned int u = __float_as_uint(f);
    u += 0x7fff + ((u >> 16) & 1);   // round-to-nearest-even
    return (unsigned short)(u >> 16);
}
static __device__ __forceinline__ float bf2f(unsigned short h) {
    return __uint_as_float(((unsigned int)h) << 16);
}
static __device__ __forceinline__ unsigned int pack2(unsigned short a, unsigned short b) {
    return (unsigned int)a | ((unsigned int)b << 16);
}

// C[M x N] = A[M x K] * B[N x K]^T via split-bf16 MFMA (a=ah+al, b=bh+bl,
// a*b ~= ah*bh + al*bh + ah*bl). Same staging/swizzle/fragment structure as
// scores_mfma (HW-verified): 64x64 tile, K-step 64, 4 waves x 16 rows.
template<int N, int K>
__global__ __launch_bounds__(256) void gemm_nt_mfma(const float* __restrict__ A,
                                                    const float* __restrict__ B,
                                                    float* __restrict__ C) {
    __shared__ __align__(16) unsigned short Ahs[64 * 64];
    __shared__ __align__(16) unsigned short Als[64 * 64];
    __shared__ __align__(16) unsigned short Bhs[64 * 64];
    __shared__ __align__(16) unsigned short Bls[64 * 64];
    const int tid  = threadIdx.x;
    const int lane = tid & 63;
    const int wid  = tid >> 6;
    const int m0   = blockIdx.y * 64, n0 = blockIdx.x * 64;

    const int sr  = tid >> 2;           // staging row 0..63
    const int sd  = (tid & 3) * 16;     // col offset within K-tile
    const int su0 = (tid & 3) * 2;      // first 16B unit

    const int kg = lane >> 4;           // k-group
    const int fr = lane & 15;           // fragment row/col index
    const int arow = wid * 16 + fr;     // A-fragment local row

    f32x4 acc[4];
#pragma unroll
    for (int t = 0; t < 4; ++t) acc[t] = (f32x4)(0.f);

    for (int kt = 0; kt < K; kt += 64) {
        // ---- stage A tile: fp32 -> bf16 hi/lo -> swizzled LDS ----
        {
            const float* ap = A + (size_t)(m0 + sr) * K + kt + sd;
            float4 a0 = *(const float4*)(ap);
            float4 a1 = *(const float4*)(ap + 4);
            float4 a2 = *(const float4*)(ap + 8);
            float4 a3 = *(const float4*)(ap + 12);
            float f[16] = {a0.x,a0.y,a0.z,a0.w, a1.x,a1.y,a1.z,a1.w,
                           a2.x,a2.y,a2.z,a2.w, a3.x,a3.y,a3.z,a3.w};
            unsigned int hw[8], lw[8];
#pragma unroll
            for (int j2 = 0; j2 < 8; ++j2) {
                unsigned short h0 = f2bf(f[2 * j2]);
                unsigned short h1 = f2bf(f[2 * j2 + 1]);
                unsigned short l0 = f2bf(f[2 * j2]     - bf2f(h0));
                unsigned short l1 = f2bf(f[2 * j2 + 1] - bf2f(h1));
                hw[j2] = pack2(h0, h1);
                lw[j2] = pack2(l0, l1);
            }
            const int p0 = ((su0     ^ (sr & 7)) << 3);
            const int p1 = (((su0+1) ^ (sr & 7)) << 3);
            *(uint4*)&Ahs[sr * 64 + p0] = make_uint4(hw[0], hw[1], hw[2], hw[3]);
            *(uint4*)&Ahs[sr * 64 + p1] = make_uint4(hw[4], hw[5], hw[6], hw[7]);
            *(uint4*)&Als[sr * 64 + p0] = make_uint4(lw[0], lw[1], lw[2], lw[3]);
            *(uint4*)&Als[sr * 64 + p1] = make_uint4(lw[4], lw[5], lw[6], lw[7]);
        }
        // ---- stage B tile ----
        {
            const float* bp = B + (size_t)(n0 + sr) * K + kt + sd;
            float4 a0 = *(const float4*)(bp);
            float4 a1 = *(const float4*)(bp + 4);
            float4 a2 = *(const float4*)(bp + 8);
            float4 a3 = *(const float4*)(bp + 12);
            float f[16] = {a0.x,a0.y,a0.z,a0.w, a1.x,a1.y,a1.z,a1.w,
                           a2.x,a2.y,a2.z,a2.w, a3.x,a3.y,a3.z,a3.w};
            unsigned int hw[8], lw[8];
#pragma unroll
            for (int j2 = 0; j2 < 8; ++j2) {
                unsigned short h0 = f2bf(f[2 * j2]);
                unsigned short h1 = f2bf(f[2 * j2 + 1]);
                unsigned short l0 = f2bf(f[2 * j2]     - bf2f(h0));
                unsigned short l1 = f2bf(f[2 * j2 + 1] - bf2f(h1));
                hw[j2] = pack2(h0, h1);
                lw[j2] = pack2(l0, l1);
            }
            const int p0 = ((su0     ^ (sr & 7)) << 3);
            const int p1 = (((su0+1) ^ (sr & 7)) << 3);
            *(uint4*)&Bhs[sr * 64 + p0] = make_uint4(hw[0], hw[1], hw[2], hw[3]);
            *(uint4*)&Bhs[sr * 64 + p1] = make_uint4(hw[4], hw[5], hw[6], hw[7]);
            *(uint4*)&Bls[sr * 64 + p0] = make_uint4(lw[0], lw[1], lw[2], lw[3]);
            *(uint4*)&Bls[sr * 64 + p1] = make_uint4(lw[4], lw[5], lw[6], lw[7]);
        }
        __syncthreads();

        // ---- MFMA: C[64m x 64n] += A @ B^T (split-bf16) ----
#pragma unroll
        for (int c = 0; c < 2; ++c) {
            const int u  = c * 4 + kg;
            const int ai = arow * 64 + ((u ^ (arow & 7)) << 3);
            bf8_t ah = *(const bf8_t*)&Ahs[ai];
            bf8_t al = *(const bf8_t*)&Als[ai];
#pragma unroll
            for (int t = 0; t < 4; ++t) {
                const int n  = t * 16 + fr;
                const int bi = n * 64 + ((u ^ (n & 7)) << 3);
                bf8_t bh = *(const bf8_t*)&Bhs[bi];
                bf8_t bl = *(const bf8_t*)&Bls[bi];
                acc[t] = __builtin_amdgcn_mfma_f32_16x16x32_bf16(ah, bh, acc[t], 0, 0, 0);
                acc[t] = __builtin_amdgcn_mfma_f32_16x16x32_bf16(al, bh, acc[t], 0, 0, 0);
                acc[t] = __builtin_amdgcn_mfma_f32_16x16x32_bf16(ah, bl, acc[t], 0, 0, 0);
            }
        }
        __syncthreads();
    }

    // ---- write C: D mapping col=lane&15, row=(lane>>4)*4+reg ----
    const int om0 = m0 + wid * 16 + (kg << 2);
#pragma unroll
    for (int j = 0; j < 4; ++j) {
        float* cp = C + (size_t)(om0 + j) * N + n0 + fr;
#pragma unroll
        for (int t = 0; t < 4; ++t)
            cp[t * 16] = acc[t][j];
    }
}

// In-place RoPE on Q and K. rotate_half: rot[i] = -x[i+32] (i<32), x[i-32] (i>=32)
__global__ __launch_bounds__(256) void rope_kernel(float* __restrict__ Q, float* __restrict__ Kp,
                                                   const float* __restrict__ cosp,
                                                   const float* __restrict__ sinp) {
    int t = blockIdx.x * 256 + threadIdx.x;   // S*H*32 threads
    int i = t & 31;
    int h = (t >> 5) & 15;
    int s = t >> 9;
    int base = s * E + h * D;
    float c0 = cosp[s * D + i], c1 = cosp[s * D + i + 32];
    float s0 = sinp[s * D + i], s1 = sinp[s * D + i + 32];
    float q0 = Q[base + i], q1 = Q[base + i + 32];
    Q[base + i]      = q0 * c0 - q1 * s0;
    Q[base + i + 32] = q1 * c1 + q0 * s1;
    float k0 = Kp[base + i], k1 = Kp[base + i + 32];
    Kp[base + i]      = k0 * c0 - k1 * s0;
    Kp[base + i + 32] = k1 * c1 + k0 * s1;
}

// Pass A (MFMA): per (head, 64 q rows): raw scaled scores -> W, online (m,l) per row.
__global__ __launch_bounds__(256) void scores_mfma(const float* __restrict__ Q,
                                                   const float* __restrict__ Kp,
                                                   float* __restrict__ W,
                                                   float* __restrict__ Mv,
                                                   float* __restrict__ Lv) {
    __shared__ __align__(16) unsigned short Khs[64 * 64];
    __shared__ __align__(16) unsigned short Kls[64 * 64];
    const int tid  = threadIdx.x;
    const int lane = tid & 63;
    const int wid  = tid >> 6;          // 4 waves, wave w owns q rows w*16..w*16+15
    const int q0   = blockIdx.x * 64;
    const int h    = blockIdx.y;

    // ---- Q fragments (hi/lo, 2 K-chunks of 32) held in registers all kernel ----
    const int qrow_frag = q0 + wid * 16 + (lane & 15);
    const float* qp = Q + (size_t)qrow_frag * E + h * D + ((lane >> 4) * 8);
    bf8_t qhi[2], qlo[2];
#pragma unroll
    for (int c = 0; c < 2; ++c) {
        float4 a = *(const float4*)(qp + c * 32);
        float4 b = *(const float4*)(qp + c * 32 + 4);
        float f[8] = {a.x, a.y, a.z, a.w, b.x, b.y, b.z, b.w};
#pragma unroll
        for (int i = 0; i < 8; ++i) {
            unsigned short hi = f2bf(f[i]);
            qhi[c][i] = (short)hi;
            qlo[c][i] = (short)f2bf(f[i] - bf2f(hi));
        }
    }

    const int sr  = tid >> 2;           // staging row 0..63
    const int sd  = (tid & 3) * 16;     // d offset
    const int su0 = (tid & 3) * 2;      // first 16B unit

    float mreg[4] = {-1e30f, -1e30f, -1e30f, -1e30f};
    float lreg[4] = {0.f, 0.f, 0.f, 0.f};
    const int wq0 = q0 + wid * 16 + ((lane >> 4) << 2);
    float* wout = W + (size_t)h * S * S;

    for (int kt = 0; kt < S; kt += 64) {
        const float* kp = Kp + (size_t)(kt + sr) * E + h * D + sd;
        float4 a0 = *(const float4*)(kp);
        float4 a1 = *(const float4*)(kp + 4);
        float4 a2 = *(const float4*)(kp + 8);
        float4 a3 = *(const float4*)(kp + 12);
        float f[16] = {a0.x,a0.y,a0.z,a0.w, a1.x,a1.y,a1.z,a1.w,
                       a2.x,a2.y,a2.z,a2.w, a3.x,a3.y,a3.z,a3.w};
        unsigned int hw[8], lw[8];
#pragma unroll
        for (int j2 = 0; j2 < 8; ++j2) {
            unsigned short h0 = f2bf(f[2 * j2]);
            unsigned short h1 = f2bf(f[2 * j2 + 1]);
            unsigned short l0 = f2bf(f[2 * j2]     - bf2f(h0));
            unsigned short l1 = f2bf(f[2 * j2 + 1] - bf2f(h1));
            hw[j2] = pack2(h0, h1);
            lw[j2] = pack2(l0, l1);
        }
        const int p0 = ((su0     ^ (sr & 7)) << 3);
        const int p1 = (((su0+1) ^ (sr & 7)) << 3);
        *(uint4*)&Khs[sr * 64 + p0] = make_uint4(hw[0], hw[1], hw[2], hw[3]);
        *(uint4*)&Khs[sr * 64 + p1] = make_uint4(hw[4], hw[5], hw[6], hw[7]);
        *(uint4*)&Kls[sr * 64 + p0] = make_uint4(lw[0], lw[1], lw[2], lw[3]);
        *(uint4*)&Kls[sr * 64 + p1] = make_uint4(lw[4], lw[5], lw[6], lw[7]);
        __syncthreads();

        f32x4 acc[4];
#pragma unroll
        for (int t = 0; t < 4; ++t) acc[t] = (f32x4)(0.f);
#pragma unroll
        for (int c = 0; c < 2; ++c) {
#pragma unroll
            for (int t = 0; t < 4; ++t) {
                const int n   = t * 16 + (lane & 15);
                const int u   = c * 4 + (lane >> 4);
                const int idx = n * 64 + ((u ^ (n & 7)) << 3);
                bf8_t kh = *(const bf8_t*)&Khs[idx];
                bf8_t kl = *(const bf8_t*)&Kls[idx];
                acc[t] = __builtin_amdgcn_mfma_f32_16x16x32_bf16(qhi[c], kh, acc[t], 0, 0, 0);
                acc[t] = __builtin_amdgcn_mfma_f32_16x16x32_bf16(qlo[c], kh, acc[t], 0, 0, 0);
                acc[t] = __builtin_amdgcn_mfma_f32_16x16x32_bf16(qhi[c], kl, acc[t], 0, 0, 0);
            }
        }

        const int col = kt + (lane & 15);
#pragma unroll
        for (int j = 0; j < 4; ++j) {
            float s0 = acc[0][j] * 0.125f;
            float s1 = acc[1][j] * 0.125f;
            float s2 = acc[2][j] * 0.125f;
            float s3 = acc[3][j] * 0.125f;
            float* wr = wout + (size_t)(wq0 + j) * S + col;
            wr[0] = s0; wr[16] = s1; wr[32] = s2; wr[48] = s3;
            float tm = fmaxf(fmaxf(s0, s1), fmaxf(s2, s3));
            float nm = fmaxf(mreg[j], tm);
            lreg[j] = lreg[j] * __expf(mreg[j] - nm)
                    + __expf(s0 - nm) + __expf(s1 - nm)
                    + __expf(s2 - nm) + __expf(s3 - nm);
            mreg[j] = nm;
        }
        __syncthreads();
    }

#pragma unroll
    for (int off = 1; off < 16; off <<= 1) {
#pragma unroll
        for (int j = 0; j < 4; ++j) {
            float om = __shfl_xor(mreg[j], off, 64);
            float ol = __shfl_xor(lreg[j], off, 64);
            float nm = fmaxf(mreg[j], om);
            lreg[j] = lreg[j] * __expf(mreg[j] - nm) + ol * __expf(om - nm);
            mreg[j] = nm;
        }
    }
    if ((lane & 15) == 0) {
#pragma unroll
        for (int j = 0; j < 4; ++j) {
            Mv[h * S + wq0 + j] = mreg[j];
            Lv[h * S + wq0 + j] = lreg[j];
        }
    }
}

// Pass B (MFMA): normalize W in place (w = exp(s-m)/l) and O = W @ V per head.
__global__ __launch_bounds__(256) void av_mfma(const float* __restrict__ V,
                                               float* __restrict__ W,
                                               const float* __restrict__ Mv,
                                               const float* __restrict__ Lv,
                                               float* __restrict__ O) {
    __shared__ __align__(16) unsigned short Phs[64 * 64];   // P[q][kv] bf16-hi, swizzled
    __shared__ __align__(16) unsigned short Pls[64 * 64];   // P lo
    __shared__ __align__(16) unsigned short Vths[64 * 64];  // V^T[d][kv] bf16-hi, swizzled
    __shared__ __align__(16) unsigned short Vtls[64 * 64];  // V^T lo
    __shared__ float sm[64], srl[64];
    const int tid  = threadIdx.x;
    const int lane = tid & 63;
    const int wid  = tid >> 6;
    const int q0   = blockIdx.x * 64;
    const int h    = blockIdx.y;

    if (tid < 64) {
        sm[tid]  = Mv[h * S + q0 + tid];
        srl[tid] = 1.0f / Lv[h * S + q0 + tid];
    }
    __syncthreads();

    const int eq   = tid >> 2;
    const int ec0  = (tid & 3) * 16;
    const int epu0 = (tid & 3) * 2;
    const int vd0 = (tid & 15) * 4;
    const int vk0 = (tid >> 4) * 4;

    float* wout = W + (size_t)h * S * S;
    const int kg = lane >> 4;
    const int arow = wid * 16 + (lane & 15);

    f32x4 acc[4];
#pragma unroll
    for (int t = 0; t < 4; ++t) acc[t] = (f32x4)(0.f);

    for (int kt = 0; kt < S; kt += 64) {
        {
            float* wrow = wout + (size_t)(q0 + eq) * S + kt + ec0;
            float4 r0 = *(const float4*)(wrow);
            float4 r1 = *(const float4*)(wrow + 4);
            float4 r2 = *(const float4*)(wrow + 8);
            float4 r3 = *(const float4*)(wrow + 12);
            float f[16] = {r0.x,r0.y,r0.z,r0.w, r1.x,r1.y,r1.z,r1.w,
                           r2.x,r2.y,r2.z,r2.w, r3.x,r3.y,r3.z,r3.w};
            const float mm = sm[eq], rl = srl[eq];
            float w[16];
#pragma unroll
            for (int j = 0; j < 16; ++j) w[j] = __expf(f[j] - mm) * rl;
            *(float4*)(wrow)      = make_float4(w[0],  w[1],  w[2],  w[3]);
            *(float4*)(wrow + 4)  = make_float4(w[4],  w[5],  w[6],  w[7]);
            *(float4*)(wrow + 8)  = make_float4(w[8],  w[9],  w[10], w[11]);
            *(float4*)(wrow + 12) = make_float4(w[12], w[13], w[14], w[15]);
            unsigned int hw[8], lw[8];
#pragma unroll
            for (int j2 = 0; j2 < 8; ++j2) {
                unsigned short h0 = f2bf(w[2 * j2]);
                unsigned short h1 = f2bf(w[2 * j2 + 1]);
                unsigned short l0 = f2bf(w[2 * j2]     - bf2f(h0));
                unsigned short l1 = f2bf(w[2 * j2 + 1] - bf2f(h1));
                hw[j2] = pack2(h0, h1);
                lw[j2] = pack2(l0, l1);
            }
            const int pb0 = eq * 64 + ((epu0       ^ (eq & 7)) << 3);
            const int pb1 = eq * 64 + (((epu0 + 1) ^ (eq & 7)) << 3);
            *(uint4*)&Phs[pb0] = make_uint4(hw[0], hw[1], hw[2], hw[3]);
            *(uint4*)&Phs[pb1] = make_uint4(hw[4], hw[5], hw[6], hw[7]);
            *(uint4*)&Pls[pb0] = make_uint4(lw[0], lw[1], lw[2], lw[3]);
            *(uint4*)&Pls[pb1] = make_uint4(lw[4], lw[5], lw[6], lw[7]);
        }
        {
            const float* vp = V + (size_t)(kt + vk0) * E + h * D + vd0;
            float vr[4][4];
#pragma unroll
            for (int r = 0; r < 4; ++r) {
                float4 t = *(const float4*)(vp + (size_t)r * E);
                vr[r][0] = t.x; vr[r][1] = t.y; vr[r][2] = t.z; vr[r][3] = t.w;
            }
#pragma unroll
            for (int d_ = 0; d_ < 4; ++d_) {
                const int d = vd0 + d_;
                unsigned short h0 = f2bf(vr[0][d_]);
                unsigned short h1 = f2bf(vr[1][d_]);
                unsigned short h2 = f2bf(vr[2][d_]);
                unsigned short h3 = f2bf(vr[3][d_]);
                unsigned short l0 = f2bf(vr[0][d_] - bf2f(h0));
                unsigned short l1 = f2bf(vr[1][d_] - bf2f(h1));
                unsigned short l2 = f2bf(vr[2][d_] - bf2f(h2));
                unsigned short l3 = f2bf(vr[3][d_] - bf2f(h3));
                const int va = d * 64 + (((vk0 >> 3) ^ (d & 7)) << 3) + (vk0 & 7);
                *(uint2*)&Vths[va] = make_uint2(pack2(h0, h1), pack2(h2, h3));
                *(uint2*)&Vtls[va] = make_uint2(pack2(l0, l1), pack2(l2, l3));
            }
        }
        __syncthreads();

#pragma unroll
        for (int kc = 0; kc < 2; ++kc) {
            const int au = ((kc * 4 + kg) ^ (arow & 7)) << 3;
            bf8_t ph = *(const bf8_t*)&Phs[arow * 64 + au];
            bf8_t pl = *(const bf8_t*)&Pls[arow * 64 + au];
#pragma unroll
            for (int t = 0; t < 4; ++t) {
                const int d  = t * 16 + (lane & 15);
                const int bu = ((kc * 4 + kg) ^ (d & 7)) << 3;
                bf8_t vh = *(const bf8_t*)&Vths[d * 64 + bu];
                bf8_t vl = *(const bf8_t*)&Vtls[d * 64 + bu];
                acc[t] = __builtin_amdgcn_mfma_f32_16x16x32_bf16(ph, vh, acc[t], 0, 0, 0);
                acc[t] = __builtin_amdgcn_mfma_f32_16x16x32_bf16(ph, vl, acc[t], 0, 0, 0);
                acc[t] = __builtin_amdgcn_mfma_f32_16x16x32_bf16(pl, vh, acc[t], 0, 0, 0);
            }
        }
        __syncthreads();
    }

    const int oq0 = q0 + wid * 16 + (kg << 2);
#pragma unroll
    for (int j = 0; j < 4; ++j) {
        float* op = O + (size_t)(oq0 + j) * E + h * D + (lane & 15);
#pragma unroll
        for (int t = 0; t < 4; ++t)
            op[t * 16] = acc[t][j];
    }
}

extern "C" void kernel_launch(void* const* d_in, const int* in_sizes, int n_in,
                              void* d_out, int out_size, void* d_ws, size_t ws_size,
                              hipStream_t stream) {
    const float* hs   = (const float*)d_in[0];
    const float* cosp = (const float*)d_in[1];
    const float* sinp = (const float*)d_in[2];
    const float* wq   = (const float*)d_in[3];
    const float* wk   = (const float*)d_in[4];
    const float* wv   = (const float*)d_in[5];
    const float* wo   = (const float*)d_in[6];

    float* out = (float*)d_out;                 // attn_output: S*E floats
    float* W   = out + (size_t)S * E;           // attn_weights: H*S*S floats

    float* ws = (float*)d_ws;
    float* Q  = ws;                             // S*E
    float* Kp = ws + (size_t)S * E;             // S*E
    float* V  = ws + 2 * (size_t)S * E;         // S*E
    float* O  = Q;                              // reuse Q region (Q dead after scores)
    float* Mv = ws + 3 * (size_t)S * E;         // H*S
    float* Lv = Mv + H * S;                     // H*S

    dim3 gproj(E / 64, S / 64);
    gemm_nt_mfma<E, E><<<gproj, 256, 0, stream>>>(hs, wq, Q);
    gemm_nt_mfma<E, E><<<gproj, 256, 0, stream>>>(hs, wk, Kp);
    gemm_nt_mfma<E, E><<<gproj, 256, 0, stream>>>(hs, wv, V);

    rope_kernel<<<(S * H * 32) / 256, 256, 0, stream>>>(Q, Kp, cosp, sinp);

    dim3 gsc(S / 64, H);
    scores_mfma<<<gsc, 256, 0, stream>>>(Q, Kp, W, Mv, Lv);

    dim3 gav(S / 64, H);
    av_mfma<<<gav, 256, 0, stream>>>(V, W, Mv, Lv, O);

    gemm_nt_mfma<E, E><<<gproj, 256, 0, stream>>>(O, wo, out);
}

// Round 5
// 1220.824 us; speedup vs baseline: 2.1320x; 1.0432x over previous
//
#include <hip/hip_runtime.h>

#define S 3136
#define E 1024
#define H 16
#define D 64
// S/64 = 49, E/64 = 16, E/128 = 8 -- all exact, no bounds checks needed.

typedef __attribute__((ext_vector_type(8))) short bf8_t;  // 8 bf16 (4 VGPRs)
typedef __attribute__((ext_vector_type(4))) float f32x4;  // 4 fp32

static __device__ __forceinline__ unsigned short f2bf(float f) {
    unsigned int u = __float_as_uint(f);
    u += 0x7fff + ((u >> 16) & 1);   // round-to-nearest-even
    return (unsigned short)(u >> 16);
}
static __device__ __forceinline__ float bf2f(unsigned short h) {
    return __uint_as_float(((unsigned int)h) << 16);
}
static __device__ __forceinline__ unsigned int pack2(unsigned short a, unsigned short b) {
    return (unsigned int)a | ((unsigned int)b << 16);
}

#define NU_HS ((S * E) / 8)     // 401408 units of 8 floats
#define NU_W  ((E * E) / 8)     // 131072 = 2^17

// One-shot fp32 -> (bf16 hi, bf16 lo) split of hs + the 4 weight matrices.
// Output layout at ub: hs_h[S*E] hs_l[S*E] wq_h wq_l wk_h wk_l wv_h wv_l wo_h wo_l (each E*E).
__global__ __launch_bounds__(256) void convert_hl(const float* __restrict__ hs,
                                                  const float* __restrict__ wq,
                                                  const float* __restrict__ wk,
                                                  const float* __restrict__ wv,
                                                  const float* __restrict__ wo,
                                                  unsigned short* __restrict__ ub) {
    const int u = blockIdx.x * 256 + threadIdx.x;
    const float* src;
    unsigned short* dh;
    unsigned short* dl;
    int idx;
    if (u < NU_HS) {
        src = hs; dh = ub; dl = ub + (size_t)S * E; idx = u;
    } else {
        const int v = u - NU_HS;
        const int w = v >> 17;            // NU_W = 2^17
        idx = v & (NU_W - 1);
        src = (w == 0) ? wq : (w == 1) ? wk : (w == 2) ? wv : wo;
        unsigned short* b = ub + 2 * (size_t)S * E + (size_t)w * 2 * E * E;
        dh = b; dl = b + (size_t)E * E;
    }
    float4 a  = ((const float4*)src)[2 * (size_t)idx];
    float4 b4 = ((const float4*)src)[2 * (size_t)idx + 1];
    float f[8] = {a.x, a.y, a.z, a.w, b4.x, b4.y, b4.z, b4.w};
    unsigned int hw[4], lw[4];
#pragma unroll
    for (int j2 = 0; j2 < 4; ++j2) {
        unsigned short h0 = f2bf(f[2 * j2]);
        unsigned short h1 = f2bf(f[2 * j2 + 1]);
        unsigned short l0 = f2bf(f[2 * j2]     - bf2f(h0));
        unsigned short l1 = f2bf(f[2 * j2 + 1] - bf2f(h1));
        hw[j2] = pack2(h0, h1);
        lw[j2] = pack2(l0, l1);
    }
    *(uint4*)(dh + 8 * (size_t)idx) = make_uint4(hw[0], hw[1], hw[2], hw[3]);
    *(uint4*)(dl + 8 * (size_t)idx) = make_uint4(lw[0], lw[1], lw[2], lw[3]);
}

// C[M x N] = A[M x K] * B[N x K]^T from pre-split bf16 hi/lo operands.
// Split-bf16: a*b ~= ah*bh + al*bh + ah*bl (3 MFMAs). Tile 64m x 128n, K-step 64,
// 4 waves each owning 64x32 output (4 m-frags x 2 n-frags); swizzled LDS (unit^row&7).
template<int N, int K>
__global__ __launch_bounds__(256) void gemm_hl_nt(const unsigned short* __restrict__ Ah,
                                                  const unsigned short* __restrict__ Al,
                                                  const unsigned short* __restrict__ Bh,
                                                  const unsigned short* __restrict__ Bl,
                                                  float* __restrict__ C) {
    __shared__ __align__(16) unsigned short Ahs[64 * 64];
    __shared__ __align__(16) unsigned short Als[64 * 64];
    __shared__ __align__(16) unsigned short Bhs[128 * 64];
    __shared__ __align__(16) unsigned short Bls[128 * 64];
    const int tid  = threadIdx.x;
    const int lane = tid & 63;
    const int wid  = tid >> 6;
    const int m0   = blockIdx.y * 64, n0 = blockIdx.x * 128;
    const int kg   = lane >> 4, fr = lane & 15;

    f32x4 acc[4][2];
#pragma unroll
    for (int m = 0; m < 4; ++m)
#pragma unroll
        for (int n = 0; n < 2; ++n) acc[m][n] = (f32x4)(0.f);

    for (int kt = 0; kt < K; kt += 64) {
        // ---- stage A (64x64 bf16 hi/lo): linear global read, swizzled LDS write ----
#pragma unroll
        for (int i = 0; i < 2; ++i) {
            const int e = tid + i * 256, r = e >> 3, lu = e & 7;
            const size_t go = (size_t)(m0 + r) * K + kt + lu * 8;
            uint4 vh = *(const uint4*)(Ah + go);
            uint4 vl = *(const uint4*)(Al + go);
            const int p = r * 64 + ((lu ^ (r & 7)) << 3);
            *(uint4*)&Ahs[p] = vh;
            *(uint4*)&Als[p] = vl;
        }
        // ---- stage B (128x64) ----
#pragma unroll
        for (int i = 0; i < 4; ++i) {
            const int e = tid + i * 256, r = e >> 3, lu = e & 7;
            const size_t go = (size_t)(n0 + r) * K + kt + lu * 8;
            uint4 vh = *(const uint4*)(Bh + go);
            uint4 vl = *(const uint4*)(Bl + go);
            const int p = r * 64 + ((lu ^ (r & 7)) << 3);
            *(uint4*)&Bhs[p] = vh;
            *(uint4*)&Bls[p] = vl;
        }
        __syncthreads();

#pragma unroll
        for (int kc = 0; kc < 2; ++kc) {
            const int u = kc * 4 + kg;
            bf8_t ah[4], al[4], bh[2], bl[2];
#pragma unroll
            for (int m = 0; m < 4; ++m) {
                const int row = m * 16 + fr;
                const int ix  = row * 64 + ((u ^ (row & 7)) << 3);
                ah[m] = *(const bf8_t*)&Ahs[ix];
                al[m] = *(const bf8_t*)&Als[ix];
            }
#pragma unroll
            for (int n = 0; n < 2; ++n) {
                const int col = wid * 32 + n * 16 + fr;
                const int ix  = col * 64 + ((u ^ (col & 7)) << 3);
                bh[n] = *(const bf8_t*)&Bhs[ix];
                bl[n] = *(const bf8_t*)&Bls[ix];
            }
#pragma unroll
            for (int m = 0; m < 4; ++m)
#pragma unroll
                for (int n = 0; n < 2; ++n) {
                    acc[m][n] = __builtin_amdgcn_mfma_f32_16x16x32_bf16(ah[m], bh[n], acc[m][n], 0, 0, 0);
                    acc[m][n] = __builtin_amdgcn_mfma_f32_16x16x32_bf16(al[m], bh[n], acc[m][n], 0, 0, 0);
                    acc[m][n] = __builtin_amdgcn_mfma_f32_16x16x32_bf16(ah[m], bl[n], acc[m][n], 0, 0, 0);
                }
        }
        __syncthreads();
    }

    // D mapping: col = lane&15 (B row), row = (lane>>4)*4 + reg (A row)
#pragma unroll
    for (int m = 0; m < 4; ++m)
#pragma unroll
        for (int n = 0; n < 2; ++n)
#pragma unroll
            for (int j = 0; j < 4; ++j)
                C[(size_t)(m0 + m * 16 + kg * 4 + j) * N + n0 + wid * 32 + n * 16 + fr] = acc[m][n][j];
}

// In-place RoPE on Q and K. rotate_half: rot[i] = -x[i+32] (i<32), x[i-32] (i>=32)
__global__ __launch_bounds__(256) void rope_kernel(float* __restrict__ Q, float* __restrict__ Kp,
                                                   const float* __restrict__ cosp,
                                                   const float* __restrict__ sinp) {
    int t = blockIdx.x * 256 + threadIdx.x;   // S*H*32 threads
    int i = t & 31;
    int h = (t >> 5) & 15;
    int s = t >> 9;
    int base = s * E + h * D;
    float c0 = cosp[s * D + i], c1 = cosp[s * D + i + 32];
    float s0 = sinp[s * D + i], s1 = sinp[s * D + i + 32];
    float q0 = Q[base + i], q1 = Q[base + i + 32];
    Q[base + i]      = q0 * c0 - q1 * s0;
    Q[base + i + 32] = q1 * c1 + q0 * s1;
    float k0 = Kp[base + i], k1 = Kp[base + i + 32];
    Kp[base + i]      = k0 * c0 - k1 * s0;
    Kp[base + i + 32] = k1 * c1 + k0 * s1;
}

// Pass A (MFMA): per (head, 64 q rows): raw scaled scores -> W, online (m,l) per row.
__global__ __launch_bounds__(256) void scores_mfma(const float* __restrict__ Q,
                                                   const float* __restrict__ Kp,
                                                   float* __restrict__ W,
                                                   float* __restrict__ Mv,
                                                   float* __restrict__ Lv) {
    __shared__ __align__(16) unsigned short Khs[64 * 64];
    __shared__ __align__(16) unsigned short Kls[64 * 64];
    const int tid  = threadIdx.x;
    const int lane = tid & 63;
    const int wid  = tid >> 6;          // 4 waves, wave w owns q rows w*16..w*16+15
    const int q0   = blockIdx.x * 64;
    const int h    = blockIdx.y;

    // ---- Q fragments (hi/lo, 2 K-chunks of 32) held in registers all kernel ----
    const int qrow_frag = q0 + wid * 16 + (lane & 15);
    const float* qp = Q + (size_t)qrow_frag * E + h * D + ((lane >> 4) * 8);
    bf8_t qhi[2], qlo[2];
#pragma unroll
    for (int c = 0; c < 2; ++c) {
        float4 a = *(const float4*)(qp + c * 32);
        float4 b = *(const float4*)(qp + c * 32 + 4);
        float f[8] = {a.x, a.y, a.z, a.w, b.x, b.y, b.z, b.w};
#pragma unroll
        for (int i = 0; i < 8; ++i) {
            unsigned short hi = f2bf(f[i]);
            qhi[c][i] = (short)hi;
            qlo[c][i] = (short)f2bf(f[i] - bf2f(hi));
        }
    }

    const int sr  = tid >> 2;           // staging row 0..63
    const int sd  = (tid & 3) * 16;     // d offset
    const int su0 = (tid & 3) * 2;      // first 16B unit

    float mreg[4] = {-1e30f, -1e30f, -1e30f, -1e30f};
    float lreg[4] = {0.f, 0.f, 0.f, 0.f};
    const int wq0 = q0 + wid * 16 + ((lane >> 4) << 2);
    float* wout = W + (size_t)h * S * S;

    for (int kt = 0; kt < S; kt += 64) {
        const float* kp = Kp + (size_t)(kt + sr) * E + h * D + sd;
        float4 a0 = *(const float4*)(kp);
        float4 a1 = *(const float4*)(kp + 4);
        float4 a2 = *(const float4*)(kp + 8);
        float4 a3 = *(const float4*)(kp + 12);
        float f[16] = {a0.x,a0.y,a0.z,a0.w, a1.x,a1.y,a1.z,a1.w,
                       a2.x,a2.y,a2.z,a2.w, a3.x,a3.y,a3.z,a3.w};
        unsigned int hw[8], lw[8];
#pragma unroll
        for (int j2 = 0; j2 < 8; ++j2) {
            unsigned short h0 = f2bf(f[2 * j2]);
            unsigned short h1 = f2bf(f[2 * j2 + 1]);
            unsigned short l0 = f2bf(f[2 * j2]     - bf2f(h0));
            unsigned short l1 = f2bf(f[2 * j2 + 1] - bf2f(h1));
            hw[j2] = pack2(h0, h1);
            lw[j2] = pack2(l0, l1);
        }
        const int p0 = ((su0     ^ (sr & 7)) << 3);
        const int p1 = (((su0+1) ^ (sr & 7)) << 3);
        *(uint4*)&Khs[sr * 64 + p0] = make_uint4(hw[0], hw[1], hw[2], hw[3]);
        *(uint4*)&Khs[sr * 64 + p1] = make_uint4(hw[4], hw[5], hw[6], hw[7]);
        *(uint4*)&Kls[sr * 64 + p0] = make_uint4(lw[0], lw[1], lw[2], lw[3]);
        *(uint4*)&Kls[sr * 64 + p1] = make_uint4(lw[4], lw[5], lw[6], lw[7]);
        __syncthreads();

        f32x4 acc[4];
#pragma unroll
        for (int t = 0; t < 4; ++t) acc[t] = (f32x4)(0.f);
#pragma unroll
        for (int c = 0; c < 2; ++c) {
#pragma unroll
            for (int t = 0; t < 4; ++t) {
                const int n   = t * 16 + (lane & 15);
                const int u   = c * 4 + (lane >> 4);
                const int idx = n * 64 + ((u ^ (n & 7)) << 3);
                bf8_t kh = *(const bf8_t*)&Khs[idx];
                bf8_t kl = *(const bf8_t*)&Kls[idx];
                acc[t] = __builtin_amdgcn_mfma_f32_16x16x32_bf16(qhi[c], kh, acc[t], 0, 0, 0);
                acc[t] = __builtin_amdgcn_mfma_f32_16x16x32_bf16(qlo[c], kh, acc[t], 0, 0, 0);
                acc[t] = __builtin_amdgcn_mfma_f32_16x16x32_bf16(qhi[c], kl, acc[t], 0, 0, 0);
            }
        }

        const int col = kt + (lane & 15);
#pragma unroll
        for (int j = 0; j < 4; ++j) {
            float s0 = acc[0][j] * 0.125f;
            float s1 = acc[1][j] * 0.125f;
            float s2 = acc[2][j] * 0.125f;
            float s3 = acc[3][j] * 0.125f;
            float* wr = wout + (size_t)(wq0 + j) * S + col;
            wr[0] = s0; wr[16] = s1; wr[32] = s2; wr[48] = s3;
            float tm = fmaxf(fmaxf(s0, s1), fmaxf(s2, s3));
            float nm = fmaxf(mreg[j], tm);
            lreg[j] = lreg[j] * __expf(mreg[j] - nm)
                    + __expf(s0 - nm) + __expf(s1 - nm)
                    + __expf(s2 - nm) + __expf(s3 - nm);
            mreg[j] = nm;
        }
        __syncthreads();
    }

#pragma unroll
    for (int off = 1; off < 16; off <<= 1) {
#pragma unroll
        for (int j = 0; j < 4; ++j) {
            float om = __shfl_xor(mreg[j], off, 64);
            float ol = __shfl_xor(lreg[j], off, 64);
            float nm = fmaxf(mreg[j], om);
            lreg[j] = lreg[j] * __expf(mreg[j] - nm) + ol * __expf(om - nm);
            mreg[j] = nm;
        }
    }
    if ((lane & 15) == 0) {
#pragma unroll
        for (int j = 0; j < 4; ++j) {
            Mv[h * S + wq0 + j] = mreg[j];
            Lv[h * S + wq0 + j] = lreg[j];
        }
    }
}

// Pass B (MFMA): normalize W in place (w = exp(s-m)/l), O = W @ V per head.
// O written directly as bf16 hi/lo (feeds the final split-bf16 GEMM).
__global__ __launch_bounds__(256) void av_mfma(const float* __restrict__ V,
                                               float* __restrict__ W,
                                               const float* __restrict__ Mv,
                                               const float* __restrict__ Lv,
                                               unsigned short* __restrict__ Oh,
                                               unsigned short* __restrict__ Ol) {
    __shared__ __align__(16) unsigned short Phs[64 * 64];   // P[q][kv] bf16-hi, swizzled
    __shared__ __align__(16) unsigned short Pls[64 * 64];   // P lo
    __shared__ __align__(16) unsigned short Vths[64 * 64];  // V^T[d][kv] bf16-hi, swizzled
    __shared__ __align__(16) unsigned short Vtls[64 * 64];  // V^T lo
    __shared__ float sm[64], srl[64];
    const int tid  = threadIdx.x;
    const int lane = tid & 63;
    const int wid  = tid >> 6;
    const int q0   = blockIdx.x * 64;
    const int h    = blockIdx.y;

    if (tid < 64) {
        sm[tid]  = Mv[h * S + q0 + tid];
        srl[tid] = 1.0f / Lv[h * S + q0 + tid];
    }
    __syncthreads();

    const int eq   = tid >> 2;
    const int ec0  = (tid & 3) * 16;
    const int epu0 = (tid & 3) * 2;
    const int vd0 = (tid & 15) * 4;
    const int vk0 = (tid >> 4) * 4;

    float* wout = W + (size_t)h * S * S;
    const int kg = lane >> 4;
    const int arow = wid * 16 + (lane & 15);

    f32x4 acc[4];
#pragma unroll
    for (int t = 0; t < 4; ++t) acc[t] = (f32x4)(0.f);

    for (int kt = 0; kt < S; kt += 64) {
        {
            float* wrow = wout + (size_t)(q0 + eq) * S + kt + ec0;
            float4 r0 = *(const float4*)(wrow);
            float4 r1 = *(const float4*)(wrow + 4);
            float4 r2 = *(const float4*)(wrow + 8);
            float4 r3 = *(const float4*)(wrow + 12);
            float f[16] = {r0.x,r0.y,r0.z,r0.w, r1.x,r1.y,r1.z,r1.w,
                           r2.x,r2.y,r2.z,r2.w, r3.x,r3.y,r3.z,r3.w};
            const float mm = sm[eq], rl = srl[eq];
            float w[16];
#pragma unroll
            for (int j = 0; j < 16; ++j) w[j] = __expf(f[j] - mm) * rl;
            *(float4*)(wrow)      = make_float4(w[0],  w[1],  w[2],  w[3]);
            *(float4*)(wrow + 4)  = make_float4(w[4],  w[5],  w[6],  w[7]);
            *(float4*)(wrow + 8)  = make_float4(w[8],  w[9],  w[10], w[11]);
            *(float4*)(wrow + 12) = make_float4(w[12], w[13], w[14], w[15]);
            unsigned int hw[8], lw[8];
#pragma unroll
            for (int j2 = 0; j2 < 8; ++j2) {
                unsigned short h0 = f2bf(w[2 * j2]);
                unsigned short h1 = f2bf(w[2 * j2 + 1]);
                unsigned short l0 = f2bf(w[2 * j2]     - bf2f(h0));
                unsigned short l1 = f2bf(w[2 * j2 + 1] - bf2f(h1));
                hw[j2] = pack2(h0, h1);
                lw[j2] = pack2(l0, l1);
            }
            const int pb0 = eq * 64 + ((epu0       ^ (eq & 7)) << 3);
            const int pb1 = eq * 64 + (((epu0 + 1) ^ (eq & 7)) << 3);
            *(uint4*)&Phs[pb0] = make_uint4(hw[0], hw[1], hw[2], hw[3]);
            *(uint4*)&Phs[pb1] = make_uint4(hw[4], hw[5], hw[6], hw[7]);
            *(uint4*)&Pls[pb0] = make_uint4(lw[0], lw[1], lw[2], lw[3]);
            *(uint4*)&Pls[pb1] = make_uint4(lw[4], lw[5], lw[6], lw[7]);
        }
        {
            const float* vp = V + (size_t)(kt + vk0) * E + h * D + vd0;
            float vr[4][4];
#pragma unroll
            for (int r = 0; r < 4; ++r) {
                float4 t = *(const float4*)(vp + (size_t)r * E);
                vr[r][0] = t.x; vr[r][1] = t.y; vr[r][2] = t.z; vr[r][3] = t.w;
            }
#pragma unroll
            for (int d_ = 0; d_ < 4; ++d_) {
                const int d = vd0 + d_;
                unsigned short h0 = f2bf(vr[0][d_]);
                unsigned short h1 = f2bf(vr[1][d_]);
                unsigned short h2 = f2bf(vr[2][d_]);
                unsigned short h3 = f2bf(vr[3][d_]);
                unsigned short l0 = f2bf(vr[0][d_] - bf2f(h0));
                unsigned short l1 = f2bf(vr[1][d_] - bf2f(h1));
                unsigned short l2 = f2bf(vr[2][d_] - bf2f(h2));
                unsigned short l3 = f2bf(vr[3][d_] - bf2f(h3));
                const int va = d * 64 + (((vk0 >> 3) ^ (d & 7)) << 3) + (vk0 & 7);
                *(uint2*)&Vths[va] = make_uint2(pack2(h0, h1), pack2(h2, h3));
                *(uint2*)&Vtls[va] = make_uint2(pack2(l0, l1), pack2(l2, l3));
            }
        }
        __syncthreads();

#pragma unroll
        for (int kc = 0; kc < 2; ++kc) {
            const int au = ((kc * 4 + kg) ^ (arow & 7)) << 3;
            bf8_t ph = *(const bf8_t*)&Phs[arow * 64 + au];
            bf8_t pl = *(const bf8_t*)&Pls[arow * 64 + au];
#pragma unroll
            for (int t = 0; t < 4; ++t) {
                const int d  = t * 16 + (lane & 15);
                const int bu = ((kc * 4 + kg) ^ (d & 7)) << 3;
                bf8_t vh = *(const bf8_t*)&Vths[d * 64 + bu];
                bf8_t vl = *(const bf8_t*)&Vtls[d * 64 + bu];
                acc[t] = __builtin_amdgcn_mfma_f32_16x16x32_bf16(ph, vh, acc[t], 0, 0, 0);
                acc[t] = __builtin_amdgcn_mfma_f32_16x16x32_bf16(ph, vl, acc[t], 0, 0, 0);
                acc[t] = __builtin_amdgcn_mfma_f32_16x16x32_bf16(pl, vh, acc[t], 0, 0, 0);
            }
        }
        __syncthreads();
    }

    const int oq0 = q0 + wid * 16 + (kg << 2);
#pragma unroll
    for (int j = 0; j < 4; ++j) {
        const size_t ob = (size_t)(oq0 + j) * E + h * D + (lane & 15);
#pragma unroll
        for (int t = 0; t < 4; ++t) {
            float x = acc[t][j];
            unsigned short hi = f2bf(x);
            unsigned short lo = f2bf(x - bf2f(hi));
            Oh[ob + t * 16] = hi;
            Ol[ob + t * 16] = lo;
        }
    }
}

extern "C" void kernel_launch(void* const* d_in, const int* in_sizes, int n_in,
                              void* d_out, int out_size, void* d_ws, size_t ws_size,
                              hipStream_t stream) {
    const float* hs   = (const float*)d_in[0];
    const float* cosp = (const float*)d_in[1];
    const float* sinp = (const float*)d_in[2];
    const float* wq   = (const float*)d_in[3];
    const float* wk   = (const float*)d_in[4];
    const float* wv   = (const float*)d_in[5];
    const float* wo   = (const float*)d_in[6];

    float* out = (float*)d_out;                 // attn_output: S*E floats
    float* W   = out + (size_t)S * E;           // attn_weights: H*S*S floats

    float* ws = (float*)d_ws;
    float* Q  = ws;                             // S*E fp32
    float* Kp = ws + (size_t)S * E;             // S*E fp32
    float* V  = ws + 2 * (size_t)S * E;         // S*E fp32
    float* Mv = ws + 3 * (size_t)S * E;         // H*S
    float* Lv = Mv + H * S;                     // H*S

    unsigned short* ub   = (unsigned short*)(Lv + H * S);
    unsigned short* hs_h = ub;                       // S*E  (reused as O_h after projections)
    unsigned short* hs_l = ub + (size_t)S * E;       // S*E  (reused as O_l)
    unsigned short* wq_h = ub + 2 * (size_t)S * E;
    unsigned short* wq_l = wq_h + (size_t)E * E;
    unsigned short* wk_h = wq_l + (size_t)E * E;
    unsigned short* wk_l = wk_h + (size_t)E * E;
    unsigned short* wv_h = wk_l + (size_t)E * E;
    unsigned short* wv_l = wv_h + (size_t)E * E;
    unsigned short* wo_h = wv_l + (size_t)E * E;
    unsigned short* wo_l = wo_h + (size_t)E * E;
    unsigned short* Oh   = hs_h;                     // overlay (hs dead after projections)
    unsigned short* Ol   = hs_l;

    convert_hl<<<(NU_HS + 4 * NU_W) / 256, 256, 0, stream>>>(hs, wq, wk, wv, wo, ub);

    dim3 gg(E / 128, S / 64);
    gemm_hl_nt<E, E><<<gg, 256, 0, stream>>>(hs_h, hs_l, wq_h, wq_l, Q);
    gemm_hl_nt<E, E><<<gg, 256, 0, stream>>>(hs_h, hs_l, wk_h, wk_l, Kp);
    gemm_hl_nt<E, E><<<gg, 256, 0, stream>>>(hs_h, hs_l, wv_h, wv_l, V);

    rope_kernel<<<(S * H * 32) / 256, 256, 0, stream>>>(Q, Kp, cosp, sinp);

    dim3 gsc(S / 64, H);
    scores_mfma<<<gsc, 256, 0, stream>>>(Q, Kp, W, Mv, Lv);

    dim3 gav(S / 64, H);
    av_mfma<<<gav, 256, 0, stream>>>(V, W, Mv, Lv, Oh, Ol);

    gemm_hl_nt<E, E><<<gg, 256, 0, stream>>>(Oh, Ol, wo_h, wo_l, out);
}